// Round 13
// baseline (161.507 us; speedup 1.0000x reference)
//
#include <hip/hip_runtime.h>

// x [32,64,64,64] f32, emb [64,1024] f32
// N = 131072 pixels, D = 64, K = 1024
// out = [ result: 8388608 f32 ][ argmin-as-f32: 131072 ]
//
// Round 17: R16 (proven 82us / absmax 0.0) with the LDS path DELETED.
// R16's counters: MFMA 70K + LDS 65K + VALU 63K cy/CU ~= duration 197K
// -> pipes serialized by the per-iter barrier phase-lock. Fix:
//  - prep writes eT in FRAGMENT ORDER [tile][ch][lane]x16B, so the
//    per-iter fragment loads are perfectly coalesced 1KB dwordx4 straight
//    into registers (R7's direct-streaming failure was the uncoalesced
//    row-major layout, not streaming itself).
//  - main loop: NO LDS, NO barriers, NO waitcnt drains. Register
//    double-buffer (static s0/s1 sets, unroll-2 bodies - rule #20).
//    Compiler counts vmcnt via dataflow; waves self-stagger and overlap
//    VMEM/MFMA/VALU across the 3 waves/SIMD.
//  - compute/scan/index-recovery/gather: R16 VERBATIM (same 17-MFMA
//    order, e2-in-MFMA, brun/bt, hi-exchange) -> absmax 0.0.
//  - __launch_bounds__(256,3): ~148 VGPR needed; no reg squeeze (R12).

using half8  = __attribute__((ext_vector_type(8))) _Float16;
using f32x16 = __attribute__((ext_vector_type(16))) float;
using u32x4  = __attribute__((ext_vector_type(4))) unsigned int;

static __device__ __forceinline__ unsigned int f16bits(_Float16 h) {
    union { _Float16 f; unsigned short u; } cv; cv.f = h; return (unsigned int)cv.u;
}

__global__ void prep_kernel(const float* __restrict__ emb,
                            unsigned int* __restrict__ e2p,
                            _Float16* __restrict__ eTph,
                            _Float16* __restrict__ eTpl) {
    const int b = blockIdx.x;
    const int tx = threadIdx.x;
    if (b < 32) {
        // fragment-ordered layout: halfs offset = t*2048 + ch*512 + l*8
        const int g  = b * 256 + tx;          // 0..8191 chunk id
        const int t  = g >> 8;                // tile 0..31
        const int ch = (g >> 6) & 3;          // 16-d chunk 0..3
        const int l  = g & 63;                // MFMA lane
        const int c  = l & 31;
        const int hi = l >> 5;
        const int k  = t * 32 + c;
        half8 hv, lv;
#pragma unroll
        for (int j = 0; j < 8; ++j) {
            float v = emb[(ch * 16 + hi * 8 + j) * 1024 + k];
            _Float16 h = (_Float16)v;          // same split as round 1
            hv[j] = h;
            lv[j] = (_Float16)(v - (float)h);  // exact residual
        }
        const int o = t * 2048 + ch * 512 + l * 8;
        *(half8*)(eTph + o) = hv;
        *(half8*)(eTpl + o) = lv;
    } else {
        // e2/2 packed split-f16 (R16-proven): exact ascending-d fmaf chain.
        const int k = (b - 32) * 256 + tx;
        float s = 0.f;
#pragma unroll
        for (int d = 0; d < 64; ++d) {
            float v = emb[(d << 10) + k];
            s = fmaf(v, v, s);
        }
        const float e2h = 0.5f * s;
        _Float16 h = (_Float16)e2h;
        _Float16 l = (_Float16)(e2h - (float)h);
        e2p[k] = f16bits(h) | (f16bits(l) << 16);
    }
}

__launch_bounds__(256, 3)
__global__ void vq_kernel(const float* __restrict__ x,
                          const _Float16* __restrict__ eTph,
                          const _Float16* __restrict__ eTpl,
                          const unsigned int* __restrict__ e2p,
                          const float* __restrict__ emb,
                          float* __restrict__ outq,
                          float* __restrict__ outidx) {
    __shared__ int samin[128];

    const int tx = threadIdx.x;
    const int n0 = blockIdx.x * 128;
    const int bb = n0 >> 12;
    const int hw = n0 & 4095;
    const float* xbase = x + bb * 262144 + hw;

    const int lane = tx & 63;
    const int w    = tx >> 6;
    const int c    = lane & 31;    // pixel col AND eT k-row
    const int hi   = lane >> 5;
    const int pxb  = w << 5;       // wave's 32-pixel base

    // ---- x fragments, NEGATED (R16 verbatim) -------------------------------
    half8 xh[4], xl[4];
#pragma unroll
    for (int ch = 0; ch < 4; ++ch) {
#pragma unroll
        for (int j = 0; j < 8; ++j) {
            float v = -xbase[(ch * 16 + hi * 8 + j) * 4096 + pxb + c];
            _Float16 h = (_Float16)v;
            xh[ch][j] = h;
            xl[ch][j] = (_Float16)(v - (float)h);
        }
    }
    asm volatile("" ::: "memory");   // keep fragments register-resident

    // ---- B = ones fragment for the e2 MFMA (R16 verbatim) ------------------
    half8 bones = {};
    if (hi == 0) { bones[0] = (_Float16)1.0f; bones[1] = (_Float16)1.0f; }

    // ---- per-lane fragment-stream bases (coalesced: lane stride 16B) -------
    const char* pH = (const char*)eTph + (lane << 4);
    const char* pL = (const char*)eTpl + (lane << 4);

    // register double-buffer sets (named scalars - no runtime indexing)
    half8 s0h0, s0h1, s0h2, s0h3, s0l0, s0l1, s0l2, s0l3;
    half8 s1h0, s1h1, s1h2, s1h3, s1l0, s1l1, s1l2, s1l3;
    unsigned int s0e, s1e;

#define LOADF(S, TT)                                                          \
    {                                                                         \
        const char* ph_ = pH + ((TT) << 12);                                  \
        const char* pl_ = pL + ((TT) << 12);                                  \
        S##h0 = *(const half8*)(ph_);                                         \
        S##h1 = *(const half8*)(ph_ + 1024);                                  \
        S##h2 = *(const half8*)(ph_ + 2048);                                  \
        S##h3 = *(const half8*)(ph_ + 3072);                                  \
        S##l0 = *(const half8*)(pl_);                                         \
        S##l1 = *(const half8*)(pl_ + 1024);                                  \
        S##l2 = *(const half8*)(pl_ + 2048);                                  \
        S##l3 = *(const half8*)(pl_ + 3072);                                  \
        S##e  = e2p[((TT) << 5) + c];                                         \
    }

    // 17-MFMA chain + scan: R16 verbatim (order preserved for bit-identity)
#define COMPF(S, TT)                                                          \
    {                                                                         \
        union { u32x4 u; half8 h; } ae2u_;                                    \
        ae2u_.u = (u32x4){ (hi == 0) ? S##e : 0u, 0u, 0u, 0u };               \
        f32x16 a = {};                                                        \
        a = __builtin_amdgcn_mfma_f32_32x32x16_f16(ae2u_.h, bones, a, 0, 0, 0); \
        a = __builtin_amdgcn_mfma_f32_32x32x16_f16(S##l0, xl[0], a, 0, 0, 0); \
        a = __builtin_amdgcn_mfma_f32_32x32x16_f16(S##l1, xl[1], a, 0, 0, 0); \
        a = __builtin_amdgcn_mfma_f32_32x32x16_f16(S##l2, xl[2], a, 0, 0, 0); \
        a = __builtin_amdgcn_mfma_f32_32x32x16_f16(S##l3, xl[3], a, 0, 0, 0); \
        a = __builtin_amdgcn_mfma_f32_32x32x16_f16(S##l0, xh[0], a, 0, 0, 0); \
        a = __builtin_amdgcn_mfma_f32_32x32x16_f16(S##l1, xh[1], a, 0, 0, 0); \
        a = __builtin_amdgcn_mfma_f32_32x32x16_f16(S##l2, xh[2], a, 0, 0, 0); \
        a = __builtin_amdgcn_mfma_f32_32x32x16_f16(S##l3, xh[3], a, 0, 0, 0); \
        a = __builtin_amdgcn_mfma_f32_32x32x16_f16(S##h0, xl[0], a, 0, 0, 0); \
        a = __builtin_amdgcn_mfma_f32_32x32x16_f16(S##h1, xl[1], a, 0, 0, 0); \
        a = __builtin_amdgcn_mfma_f32_32x32x16_f16(S##h2, xl[2], a, 0, 0, 0); \
        a = __builtin_amdgcn_mfma_f32_32x32x16_f16(S##h3, xl[3], a, 0, 0, 0); \
        a = __builtin_amdgcn_mfma_f32_32x32x16_f16(S##h0, xh[0], a, 0, 0, 0); \
        a = __builtin_amdgcn_mfma_f32_32x32x16_f16(S##h1, xh[1], a, 0, 0, 0); \
        a = __builtin_amdgcn_mfma_f32_32x32x16_f16(S##h2, xh[2], a, 0, 0, 0); \
        a = __builtin_amdgcn_mfma_f32_32x32x16_f16(S##h3, xh[3], a, 0, 0, 0); \
        _Pragma("unroll")                                                     \
        for (int r = 0; r < 16; ++r) brun[r] = fminf(brun[r], a[r]);          \
        float m0 = fminf(fminf(a[0], a[1]),   fminf(a[2], a[3]));             \
        float m1 = fminf(fminf(a[4], a[5]),   fminf(a[6], a[7]));             \
        float m2 = fminf(fminf(a[8], a[9]),   fminf(a[10], a[11]));           \
        float m3 = fminf(fminf(a[12], a[13]), fminf(a[14], a[15]));           \
        float m  = fminf(fminf(m0, m1), fminf(m2, m3));                       \
        if (m < best) bt = (TT);                                              \
        best = fminf(best, m);                                                \
    }

    float brun[16];
#pragma unroll
    for (int i = 0; i < 16; ++i) brun[i] = 3.4e38f;
    float best = 3.4e38f;
    int   bt   = 0;

    // ---- barrier-free streamed loop: load next set while computing ---------
    LOADF(s0, 0);
#pragma unroll 1
    for (int t = 0; t < 30; t += 2) {
        LOADF(s1, t + 1);
        COMPF(s0, t)
        LOADF(s0, t + 2);
        COMPF(s1, t + 1)
    }
    LOADF(s1, 31);
    COMPF(s0, 30)
    COMPF(s1, 31)

    // ---- index recovery (R16 verbatim) -------------------------------------
    int rst = 0;
#pragma unroll
    for (int rr = 15; rr >= 0; --rr)
        if (brun[rr] == best) rst = rr;
    const int row = (rst & 3) + 8 * (rst >> 2) + 4 * hi;   // k_local (m74/m101)
    int bk = (bt << 5) + row;

    // ---- hi-half exchange: the two lanes of pixel pxb+c merge (v,k) --------
    {
        float ov = __shfl_xor(best, 32, 64);
        int   ok = __shfl_xor(bk, 32, 64);
        if (ov < best || (ov == best && ok < bk)) { best = ov; bk = ok; }
    }

    if (lane < 32) samin[pxb + c] = bk;
    __syncthreads();

    if (tx < 128) outidx[n0 + tx] = (float)samin[tx];

    // ---- gather exact fp32 codebook rows -> output (R16 verbatim) ----------
    const int p = tx & 127;
    const int drow = tx >> 7;                 // 0 or 1
    const int amin = samin[p];
    float* obase = outq + bb * 262144 + hw + p;
#pragma unroll
    for (int it = 0; it < 32; ++it) {
        int d = (it << 1) + drow;
        obase[d * 4096] = emb[d * 1024 + amin];
    }
}

extern "C" void kernel_launch(void* const* d_in, const int* in_sizes, int n_in,
                              void* d_out, int out_size, void* d_ws, size_t ws_size,
                              hipStream_t stream) {
    const float* x   = (const float*)d_in[0];
    const float* emb = (const float*)d_in[1];
    float* outq   = (float*)d_out;
    float* outidx = outq + 8388608;            // 32*64*64*64

    unsigned int* e2p  = (unsigned int*)d_ws;                      // 4 KB
    _Float16*     eTph = (_Float16*)((char*)d_ws + 4096);          // 128 KB
    _Float16*     eTpl = (_Float16*)((char*)d_ws + 4096 + 131072); // 128 KB

    prep_kernel<<<36, 256, 0, stream>>>(emb, e2p, eTph, eTpl);
    vq_kernel<<<1024, 256, 0, stream>>>(x, eTph, eTpl, e2p, emb, outq, outidx);
}